// Round 2
// baseline (1534.311 us; speedup 1.0000x reference)
//
#include <hip/hip_runtime.h>

#define LQ_ 21760
#define LIN_ 21760
#define BATCH_ 2
#define CDIM 256
#define NHEAD 8
#define HDIM 32

// C[M,N] = A[M,256] @ W[256,N] + bias, fp32.
// grid.x = M/8, block = N/2 threads (thread j handles cols 2j, 2j+1).
template <int N>
__launch_bounds__(N / 2)
__global__ void gemm_bias8(const float* __restrict__ A, const float* __restrict__ W,
                           const float* __restrict__ bias, float* __restrict__ out) {
  const int r0 = blockIdx.x * 8;
  const int j = threadIdx.x * 2;
  const float* Arow = A + (size_t)r0 * CDIM;
  float acc0[8], acc1[8];
#pragma unroll
  for (int r = 0; r < 8; ++r) {
    acc0[r] = 0.f;
    acc1[r] = 0.f;
  }
  for (int k0 = 0; k0 < CDIM; k0 += 4) {
    float4 a[8];
#pragma unroll
    for (int r = 0; r < 8; ++r) {
      a[r] = *(const float4*)(Arow + r * CDIM + k0);  // thread-uniform -> scalar loads
    }
#pragma unroll
    for (int kp = 0; kp < 4; ++kp) {
      const float2 w = *(const float2*)(W + (size_t)(k0 + kp) * N + j);
#pragma unroll
      for (int r = 0; r < 8; ++r) {
        const float av = (kp == 0) ? a[r].x : (kp == 1) ? a[r].y : (kp == 2) ? a[r].z : a[r].w;
        acc0[r] += av * w.x;
        acc1[r] += av * w.y;
      }
    }
  }
  const float b0 = bias[j];
  const float b1 = bias[j + 1];
#pragma unroll
  for (int r = 0; r < 8; ++r) {
    float2 o;
    o.x = acc0[r] + b0;
    o.y = acc1[r] + b1;
    *(float2*)(out + (size_t)(r0 + r) * N + j) = o;
  }
}

// One block per (b,q); 256 threads: t -> (head = t>>5, dim = t&31).
__launch_bounds__(256)
__global__ void msda_sample(const float* __restrict__ value, const float* __restrict__ off,
                            const float* __restrict__ attnl, const float* __restrict__ refp,
                            float* __restrict__ out) {
  __shared__ float s_off[CDIM];
  __shared__ float s_aw[NHEAD * 16];
  __shared__ float s_ref[8];
  const int bq = blockIdx.x;
  const int t = threadIdx.x;
  s_off[t] = off[(size_t)bq * CDIM + t];
  if (t < 128) s_aw[t] = attnl[(size_t)bq * 128 + t];
  if (t < 8) s_ref[t] = refp[(size_t)bq * 8 + t];
  __syncthreads();
  if (t < NHEAD) {
    float m = -1e30f;
#pragma unroll
    for (int i = 0; i < 16; ++i) m = fmaxf(m, s_aw[t * 16 + i]);
    float s = 0.f;
#pragma unroll
    for (int i = 0; i < 16; ++i) {
      const float e = __expf(s_aw[t * 16 + i] - m);
      s_aw[t * 16 + i] = e;
      s += e;
    }
    const float inv = 1.f / s;
#pragma unroll
    for (int i = 0; i < 16; ++i) s_aw[t * 16 + i] *= inv;
  }
  __syncthreads();

  const int h = t >> 5, d = t & 31;
  const int b = (bq >= LQ_) ? 1 : 0;
  const float* vbase = value + (size_t)b * LIN_ * CDIM + h * HDIM + d;

  const int WL[4] = {128, 64, 32, 16};
  const int HL[4] = {128, 64, 32, 16};
  const int ST[4] = {0, 16384, 20480, 21504};

  float acc = 0.f;
#pragma unroll
  for (int l = 0; l < 4; ++l) {
    const int Wl = WL[l], Hl = HL[l], st = ST[l];
    const float rx = s_ref[l * 2 + 0];
    const float ry = s_ref[l * 2 + 1];
#pragma unroll
    for (int p = 0; p < 4; ++p) {
      const int ob = ((h * 4 + l) * 4 + p) * 2;
      const float x = rx * (float)Wl + s_off[ob + 0] - 0.5f;
      const float y = ry * (float)Hl + s_off[ob + 1] - 0.5f;
      const float aw = s_aw[h * 16 + l * 4 + p];
      const float xf = floorf(x), yf = floorf(y);
      const int x0 = (int)xf, y0 = (int)yf;
      const float lw = x - xf, lh = y - yf;
      const float hw = 1.f - lw, hh = 1.f - lh;

      float sample = 0.f;
      {
        const bool valid = (x0 >= 0) & (x0 < Wl) & (y0 >= 0) & (y0 < Hl);
        int idx = y0 * Wl + x0;
        idx = max(0, min(idx, Hl * Wl - 1));
        const float v = vbase[(size_t)(st + idx) * CDIM];
        sample += valid ? (hw * hh) * v : 0.f;
      }
      {
        const int ix = x0 + 1;
        const bool valid = (ix >= 0) & (ix < Wl) & (y0 >= 0) & (y0 < Hl);
        int idx = y0 * Wl + ix;
        idx = max(0, min(idx, Hl * Wl - 1));
        const float v = vbase[(size_t)(st + idx) * CDIM];
        sample += valid ? (lw * hh) * v : 0.f;
      }
      {
        const int iy = y0 + 1;
        const bool valid = (x0 >= 0) & (x0 < Wl) & (iy >= 0) & (iy < Hl);
        int idx = iy * Wl + x0;
        idx = max(0, min(idx, Hl * Wl - 1));
        const float v = vbase[(size_t)(st + idx) * CDIM];
        sample += valid ? (hw * lh) * v : 0.f;
      }
      {
        const int ix = x0 + 1, iy = y0 + 1;
        const bool valid = (ix >= 0) & (ix < Wl) & (iy >= 0) & (iy < Hl);
        int idx = iy * Wl + ix;
        idx = max(0, min(idx, Hl * Wl - 1));
        const float v = vbase[(size_t)(st + idx) * CDIM];
        sample += valid ? (lw * lh) * v : 0.f;
      }
      acc += aw * sample;
    }
  }
  out[(size_t)bq * CDIM + t] = acc;
}

extern "C" void kernel_launch(void* const* d_in, const int* in_sizes, int n_in,
                              void* d_out, int out_size, void* d_ws, size_t ws_size,
                              hipStream_t stream) {
  const float* query = (const float*)d_in[0];
  const float* refp = (const float*)d_in[1];
  const float* inflat = (const float*)d_in[2];
  const float* Wv = (const float*)d_in[3];
  const float* bv = (const float*)d_in[4];
  const float* Wof = (const float*)d_in[5];
  const float* bof = (const float*)d_in[6];
  const float* Wa = (const float*)d_in[7];
  const float* ba = (const float*)d_in[8];
  const float* Wo = (const float*)d_in[9];
  const float* bo = (const float*)d_in[10];
  float* out = (float*)d_out;

  const int M = BATCH_ * LQ_;  // 43520

  float* ws_value = (float*)d_ws;                    // M*256 fp32
  float* ws_off = ws_value + (size_t)M * 256;        // M*256
  float* ws_attn = ws_off + (size_t)M * 256;         // M*128
  float* ws_samp = ws_attn + (size_t)M * 128;        // M*256

  const dim3 g(M / 8);
  hipLaunchKernelGGL((gemm_bias8<256>), g, dim3(128), 0, stream, inflat, Wv, bv, ws_value);
  hipLaunchKernelGGL((gemm_bias8<256>), g, dim3(128), 0, stream, query, Wof, bof, ws_off);
  hipLaunchKernelGGL((gemm_bias8<128>), g, dim3(64), 0, stream, query, Wa, ba, ws_attn);
  hipLaunchKernelGGL(msda_sample, dim3(M), dim3(256), 0, stream, ws_value, ws_off, ws_attn,
                     refp, ws_samp);
  hipLaunchKernelGGL((gemm_bias8<256>), g, dim3(128), 0, stream, ws_samp, Wo, bo, out);
}

// Round 4
// 408.599 us; speedup vs baseline: 3.7551x; 3.7551x over previous
//
#include <hip/hip_runtime.h>

typedef unsigned short u16;
typedef unsigned int u32;
typedef short bf16x8 __attribute__((ext_vector_type(8)));
typedef float f32x4 __attribute__((ext_vector_type(4)));

#define LQ_ 21760
#define LIN_ 21760
#define CDIM 256

__device__ __forceinline__ u16 f2bf(float f) {
  u32 u;
  __builtin_memcpy(&u, &f, 4);
  u32 r = (u + 0x7fffu + ((u >> 16) & 1u)) >> 16;
  return (u16)r;
}
__device__ __forceinline__ u32 pack_bf16_rne(float a, float b) {
  return (u32)f2bf(a) | ((u32)f2bf(b) << 16);
}
__device__ __forceinline__ float bflo(u32 u) {
  u32 v = u << 16;
  float f;
  __builtin_memcpy(&f, &v, 4);
  return f;
}
__device__ __forceinline__ float bfhi(u32 u) {
  u32 v = u & 0xffff0000u;
  float f;
  __builtin_memcpy(&f, &v, 4);
  return f;
}

// C[M,N] = A[M,256] @ W[256,N] + bias.  bf16 MFMA 16x16x32 internally.
// Block: 256 threads = 4 waves; tile 64 rows x N cols; BK=32, 8 k-steps.
// LDS tiles stored in FRAGMENT ORDER: elem offset (row|n, k) =
//   (rc>>4)*512 + (k>>3)*128 + (rc&15)*8 + (k&7)   -> frag read = b128 @ lane*16.
template <int N, typename AT, typename OT>
__launch_bounds__(256)
__global__ void gemm_mfma(const AT* __restrict__ A, const float* __restrict__ W,
                          const float* __restrict__ bias, OT* __restrict__ out) {
  constexpr int NT = N / 16;
  __shared__ u16 sA[64 * 32];
  __shared__ u16 sW[N * 32];
  const int t = threadIdx.x;
  const int wv = t >> 6;
  const int l = t & 63;
  const int r0 = blockIdx.x * 64;

  f32x4 acc[NT];
#pragma unroll
  for (int c = 0; c < NT; ++c) acc[c] = f32x4{0.f, 0.f, 0.f, 0.f};

  const int arow = t >> 2;          // 0..63
  const int akq = (t & 3) * 8;      // 0,8,16,24
  const int kc = t & 3;             // W stage k-chunk
  u16* sAp = sA + (arow >> 4) * 512 + (akq >> 3) * 128 + (arow & 15) * 8;

  for (int k0 = 0; k0 < CDIM; k0 += 32) {
    __syncthreads();
    // ---- stage A tile (64 x 32) ----
    if constexpr (sizeof(AT) == 4) {
      const float* ap = (const float*)A + (size_t)(r0 + arow) * CDIM + k0 + akq;
      const float4 f0 = *(const float4*)ap;
      const float4 f1 = *(const float4*)(ap + 4);
      uint4 pk;
      pk.x = pack_bf16_rne(f0.x, f0.y);
      pk.y = pack_bf16_rne(f0.z, f0.w);
      pk.z = pack_bf16_rne(f1.x, f1.y);
      pk.w = pack_bf16_rne(f1.z, f1.w);
      *(uint4*)sAp = pk;
    } else {
      const u16* ap = (const u16*)A + (size_t)(r0 + arow) * CDIM + k0 + akq;
      *(uint4*)sAp = *(const uint4*)ap;
    }
    // ---- stage W tile (32 x N) transposed to frag order ----
#pragma unroll
    for (int p = 0; p < N / 64; ++p) {
      const int n = (t >> 2) + p * 64;
      float w[8];
#pragma unroll
      for (int j = 0; j < 8; ++j) w[j] = W[(size_t)(k0 + kc * 8 + j) * N + n];
      uint4 pk;
      pk.x = pack_bf16_rne(w[0], w[1]);
      pk.y = pack_bf16_rne(w[2], w[3]);
      pk.z = pack_bf16_rne(w[4], w[5]);
      pk.w = pack_bf16_rne(w[6], w[7]);
      *(uint4*)(sW + (n >> 4) * 512 + kc * 128 + (n & 15) * 8) = pk;
    }
    __syncthreads();
    // ---- MFMA ----
    const bf16x8 afrag = *(const bf16x8*)(sA + wv * 512 + l * 8);
#pragma unroll
    for (int c = 0; c < NT; ++c) {
      const bf16x8 bfrag = *(const bf16x8*)(sW + c * 512 + l * 8);
      acc[c] = __builtin_amdgcn_mfma_f32_16x16x32_bf16(afrag, bfrag, acc[c], 0, 0, 0);
    }
  }
  // ---- epilogue: C/D layout col=l&15, row=(l>>4)*4+r ----
  const int col0 = l & 15;
  const int rq = (l >> 4) * 4;
#pragma unroll
  for (int c = 0; c < NT; ++c) {
    const int col = c * 16 + col0;
    const float bz = bias[col];
#pragma unroll
    for (int r = 0; r < 4; ++r) {
      const int row = r0 + wv * 16 + rq + r;
      const float v = acc[c][r] + bz;
      if constexpr (sizeof(OT) == 4) {
        ((float*)out)[(size_t)row * N + col] = v;
      } else {
        ((u16*)out)[(size_t)row * N + col] = f2bf(v);
      }
    }
  }
}

// Sampler: 4 queries per 256-thread block.
// Phase 0: 32 threads -> softmax per (q,h).
// Phase 1: 512 items (q,h,l,p) -> 4 corner row-indices + fused weights into LDS.
// Phase 2: thread = (q, h, dim-group of 4) -> 64 x 8B bf16 gathers + FMA.
__launch_bounds__(256)
__global__ void msda_sample2(const u16* __restrict__ value, const float* __restrict__ off,
                             const float* __restrict__ attnl, const float* __restrict__ refp,
                             u16* __restrict__ out) {
  __shared__ float s_aw[32 * 17];
  __shared__ u32 s_ent[16 * 32 * 9];  // (lp,qh): [idx0..3, w0..3, pad]
  const int t = threadIdx.x;
  const int bq0 = blockIdx.x * 4;

  if (t < 32) {
    const int q = t >> 3, h = t & 7;
    const float* lg = attnl + (size_t)(bq0 + q) * 128 + h * 16;
    float e[16];
    float m = -1e30f;
#pragma unroll
    for (int i = 0; i < 16; ++i) {
      e[i] = lg[i];
      m = fmaxf(m, e[i]);
    }
    float s = 0.f;
#pragma unroll
    for (int i = 0; i < 16; ++i) {
      e[i] = __expf(e[i] - m);
      s += e[i];
    }
    const float inv = 1.f / s;
#pragma unroll
    for (int i = 0; i < 16; ++i) s_aw[t * 17 + i] = e[i] * inv;
  }
  __syncthreads();

#pragma unroll
  for (int rr = 0; rr < 2; ++rr) {
    const int id = t + rr * 256;
    const int qh = id & 31, lp = id >> 5;
    const int q = qh >> 3, h = qh & 7, lv = lp >> 2, p = lp & 3;
    const int bq = bq0 + q;
    const int Wl = 128 >> lv;
    const int Hl = Wl;
    const int st = (lv == 0) ? 0 : (lv == 1) ? 16384 : (lv == 2) ? 20480 : 21504;
    const float ox = off[(size_t)bq * 256 + (size_t)(((h * 4 + lv) * 4 + p) * 2)];
    const float oy = off[(size_t)bq * 256 + (size_t)(((h * 4 + lv) * 4 + p) * 2) + 1];
    const float rx = refp[(size_t)bq * 8 + lv * 2];
    const float ry = refp[(size_t)bq * 8 + lv * 2 + 1];
    const float aw = s_aw[qh * 17 + lp];
    const float x = rx * (float)Wl + ox - 0.5f;
    const float y = ry * (float)Hl + oy - 0.5f;
    const float xf = floorf(x), yf = floorf(y);
    const int x0 = (int)xf, y0 = (int)yf;
    const float lw = x - xf, lh = y - yf;
    const float hw = 1.f - lw, hh = 1.f - lh;
    const u32 base = (u32)(lp * 32 + qh) * 9;
    const int ixs[4] = {x0, x0 + 1, x0, x0 + 1};
    const int iys[4] = {y0, y0, y0 + 1, y0 + 1};
    const float ws[4] = {hw * hh, lw * hh, hw * lh, lw * lh};
#pragma unroll
    for (int c = 0; c < 4; ++c) {
      const int ix = ixs[c], iy = iys[c];
      const bool valid = (ix >= 0) & (ix < Wl) & (iy >= 0) & (iy < Hl);
      int idx = iy * Wl + ix;
      idx = max(0, min(idx, Hl * Wl - 1));
      s_ent[base + c] = (u32)(st + idx);
      s_ent[base + 4 + c] = __float_as_uint(valid ? (ws[c] * aw) : 0.f);
    }
  }
  __syncthreads();

  const int q = t >> 6, qh = t >> 3, h = (t >> 3) & 7, dg = t & 7;
  const int bq = bq0 + q;
  const size_t vb = (size_t)((bq >= LQ_) ? LIN_ : 0) * CDIM;
  const u16* vp = value + vb + h * 32 + dg * 4;
  float a0 = 0.f, a1 = 0.f, a2 = 0.f, a3 = 0.f;
#pragma unroll 4
  for (int lp = 0; lp < 16; ++lp) {
    const u32 base = (u32)(lp * 32 + qh) * 9;
#pragma unroll
    for (int c = 0; c < 4; ++c) {
      const u32 row = s_ent[base + c];
      const float w = __uint_as_float(s_ent[base + 4 + c]);
      const u32* pv = (const u32*)(vp + (size_t)row * CDIM);
      const u32 d01 = pv[0];
      const u32 d23 = pv[1];
      a0 += w * bflo(d01);
      a1 += w * bfhi(d01);
      a2 += w * bflo(d23);
      a3 += w * bfhi(d23);
    }
  }
  uint2 o;
  o.x = pack_bf16_rne(a0, a1);
  o.y = pack_bf16_rne(a2, a3);
  *(uint2*)(out + (size_t)bq * CDIM + h * 32 + dg * 4) = o;
}

extern "C" void kernel_launch(void* const* d_in, const int* in_sizes, int n_in,
                              void* d_out, int out_size, void* d_ws, size_t ws_size,
                              hipStream_t stream) {
  const float* query = (const float*)d_in[0];
  const float* refp = (const float*)d_in[1];
  const float* inflat = (const float*)d_in[2];
  const float* Wv = (const float*)d_in[3];
  const float* bv = (const float*)d_in[4];
  const float* Wof = (const float*)d_in[5];
  const float* bof = (const float*)d_in[6];
  const float* Wa = (const float*)d_in[7];
  const float* ba = (const float*)d_in[8];
  const float* Wo = (const float*)d_in[9];
  const float* bo = (const float*)d_in[10];
  float* out = (float*)d_out;

  const int M = 2 * LQ_;  // 43520

  u16* ws_value = (u16*)d_ws;                       // M*256 bf16
  u16* ws_samp = ws_value + (size_t)M * 256;        // M*256 bf16
  float* ws_off = (float*)(ws_samp + (size_t)M * 256);  // M*256 f32
  float* ws_attn = ws_off + (size_t)M * 256;        // M*128 f32

  const dim3 g64(M / 64);
  hipLaunchKernelGGL((gemm_mfma<256, float, u16>), g64, dim3(256), 0, stream,
                     inflat, Wv, bv, ws_value);
  hipLaunchKernelGGL((gemm_mfma<256, float, float>), g64, dim3(256), 0, stream,
                     query, Wof, bof, ws_off);
  hipLaunchKernelGGL((gemm_mfma<128, float, float>), g64, dim3(256), 0, stream,
                     query, Wa, ba, ws_attn);
  hipLaunchKernelGGL(msda_sample2, dim3(M / 4), dim3(256), 0, stream,
                     ws_value, ws_off, ws_attn, refp, ws_samp);
  hipLaunchKernelGGL((gemm_mfma<256, u16, float>), g64, dim3(256), 0, stream,
                     ws_samp, Wo, bo, out);
}

// Round 6
// 292.007 us; speedup vs baseline: 5.2544x; 1.3993x over previous
//
#include <hip/hip_runtime.h>

typedef unsigned short u16;
typedef unsigned int u32;
typedef short bf16x8 __attribute__((ext_vector_type(8)));
typedef float f32x4 __attribute__((ext_vector_type(4)));

#define LQ_ 21760
#define LIN_ 21760
#define CDIM 256

__device__ __forceinline__ u16 f2bf(float f) {
  u32 u;
  __builtin_memcpy(&u, &f, 4);
  u32 r = (u + 0x7fffu + ((u >> 16) & 1u)) >> 16;
  return (u16)r;
}
__device__ __forceinline__ u32 pack_bf16_rne(float a, float b) {
  return (u32)f2bf(a) | ((u32)f2bf(b) << 16);
}
__device__ __forceinline__ float bflo(u32 u) {
  u32 v = u << 16;
  float f;
  __builtin_memcpy(&f, &v, 4);
  return f;
}
__device__ __forceinline__ float bfhi(u32 u) {
  u32 v = u & 0xffff0000u;
  float f;
  __builtin_memcpy(&f, &v, 4);
  return f;
}

// ---------- weight pre-conversion to bf16 fragment-chunk layout ----------
// Chunk (ks, c, kcr): ks = k0/32 (0..7), c = n>>4, kcr = (k>>3)&3.
// chunkIdx = ks*(N/4) + c*4 + kcr ; element (n&15)*8 + (k&7).
// A GEMM block at (cb, ks) then reads 32 CONTIGUOUS chunks -> linear uint4 copy.
__device__ __forceinline__ void conv_one(const float* W0, const float* W1, u16* Wf,
                                         int N, int split, int blk, int t) {
  const int tid = blk * 256 + t;
  if (tid >= N * 32) return;
  const int n = tid >> 5, kcg = tid & 31;
  float w[8];
#pragma unroll
  for (int j = 0; j < 8; ++j) {
    const int k = kcg * 8 + j;
    w[j] = (n < split) ? W0[(size_t)k * split + n]
                       : W1[(size_t)k * (N - split) + (n - split)];
  }
  uint4 pk;
  pk.x = pack_bf16_rne(w[0], w[1]);
  pk.y = pack_bf16_rne(w[2], w[3]);
  pk.z = pack_bf16_rne(w[4], w[5]);
  pk.w = pack_bf16_rne(w[6], w[7]);
  const int ks = kcg >> 2, kcr = kcg & 3, c = n >> 4;
  const int chunk = ks * (N / 4) + c * 4 + kcr;
  *(uint4*)(Wf + (size_t)chunk * 128 + (n & 15) * 8) = pk;
}

__global__ __launch_bounds__(256) void conv_all(
    const float* __restrict__ Wv, const float* __restrict__ Wof,
    const float* __restrict__ Wa, const float* __restrict__ Wo,
    const float* __restrict__ bof, const float* __restrict__ ba,
    u16* __restrict__ WfV, u16* __restrict__ WfC, u16* __restrict__ WfO,
    float* __restrict__ bcat) {
  const int b = blockIdx.x, t = threadIdx.x;
  if (b < 32) {
    conv_one(Wv, Wv, WfV, 256, 256, b, t);
  } else if (b < 80) {
    conv_one(Wof, Wa, WfC, 384, 256, b - 32, t);
  } else if (b < 112) {
    conv_one(Wo, Wo, WfO, 256, 256, b - 80, t);
  } else {
    const int i = (b - 112) * 256 + t;
    if (i < 384) bcat[i] = (i < 256) ? bof[i] : ba[i - 256];
  }
}

// ---------- shared MFMA tile core (macro-free, inlined by hand) ----------
// Block: 256 thr = 4 waves (2x2), tile 128x128, BK=32, 8 k-steps.
// sA/sB in fragment order: chunk ((rc>>4)*4 + (k>>3))*128 + (rc&15)*8 + (k&7).

// GEMM 1: value = inflat(f32) @ WfV + bv -> bf16 out, N=256
__global__ __launch_bounds__(256) void gemm_value(
    const float* __restrict__ A, const u16* __restrict__ Wf,
    const float* __restrict__ bias, u16* __restrict__ out) {
  __shared__ u16 sA[128 * 32];
  __shared__ u16 sB[128 * 32];
  const int rb = blockIdx.x >> 1, cb = blockIdx.x & 1;
  const int r0 = rb * 128;
  const int t = threadIdx.x, l = t & 63, wv = t >> 6;
  const int wr = wv >> 1, wc = wv & 1;
  const int fq = l >> 4, fr = l & 15;
  f32x4 acc[4][4];
#pragma unroll
  for (int r = 0; r < 4; ++r)
#pragma unroll
    for (int c = 0; c < 4; ++c) acc[r][c] = f32x4{0.f, 0.f, 0.f, 0.f};
  const int ar = t >> 1, kh = t & 1;
  u16* sA0 = sA + ((ar >> 4) * 4 + kh * 2) * 128 + (ar & 15) * 8;
  for (int ks = 0; ks < 8; ++ks) {
    __syncthreads();
    const float* ap = A + (size_t)(r0 + ar) * CDIM + ks * 32 + kh * 16;
    const float4 f0 = *(const float4*)ap;
    const float4 f1 = *(const float4*)(ap + 4);
    const float4 f2 = *(const float4*)(ap + 8);
    const float4 f3 = *(const float4*)(ap + 12);
    uint4 p0, p1;
    p0.x = pack_bf16_rne(f0.x, f0.y);
    p0.y = pack_bf16_rne(f0.z, f0.w);
    p0.z = pack_bf16_rne(f1.x, f1.y);
    p0.w = pack_bf16_rne(f1.z, f1.w);
    p1.x = pack_bf16_rne(f2.x, f2.y);
    p1.y = pack_bf16_rne(f2.z, f2.w);
    p1.z = pack_bf16_rne(f3.x, f3.y);
    p1.w = pack_bf16_rne(f3.z, f3.w);
    *(uint4*)sA0 = p0;
    *(uint4*)(sA0 + 128) = p1;
    const u16* wsrc = Wf + ((size_t)ks * 64 + cb * 32) * 128 + t * 16;
    *(uint4*)(sB + t * 16) = *(const uint4*)wsrc;
    *(uint4*)(sB + t * 16 + 8) = *(const uint4*)(wsrc + 8);
    __syncthreads();
    bf16x8 af[4];
#pragma unroll
    for (int r = 0; r < 4; ++r)
      af[r] = *(const bf16x8*)(sA + ((wr * 4 + r) * 4 + fq) * 128 + fr * 8);
#pragma unroll
    for (int c = 0; c < 4; ++c) {
      const bf16x8 bf = *(const bf16x8*)(sB + ((wc * 4 + c) * 4 + fq) * 128 + fr * 8);
#pragma unroll
      for (int r = 0; r < 4; ++r)
        acc[r][c] = __builtin_amdgcn_mfma_f32_16x16x32_bf16(af[r], bf, acc[r][c], 0, 0, 0);
    }
  }
  const int rq = fq * 4;
#pragma unroll
  for (int c = 0; c < 4; ++c) {
    const int col = cb * 128 + wc * 64 + c * 16 + fr;
    const float bz = bias[col];
#pragma unroll
    for (int r = 0; r < 4; ++r) {
      const int row0 = r0 + wr * 64 + r * 16 + rq;
#pragma unroll
      for (int g = 0; g < 4; ++g)
        out[(size_t)(row0 + g) * 256 + col] = f2bf(acc[r][c][g] + bz);
    }
  }
}

// GEMM 2: [off|attn] = query(f32) @ WfC + bcat -> f32 split stores, N=384
__global__ __launch_bounds__(256) void gemm_qc(
    const float* __restrict__ A, const u16* __restrict__ Wf,
    const float* __restrict__ bias, float* __restrict__ outO,
    float* __restrict__ outA) {
  __shared__ u16 sA[128 * 32];
  __shared__ u16 sB[128 * 32];
  const int rb = blockIdx.x / 3, cb = blockIdx.x % 3;
  const int r0 = rb * 128;
  const int t = threadIdx.x, l = t & 63, wv = t >> 6;
  const int wr = wv >> 1, wc = wv & 1;
  const int fq = l >> 4, fr = l & 15;
  f32x4 acc[4][4];
#pragma unroll
  for (int r = 0; r < 4; ++r)
#pragma unroll
    for (int c = 0; c < 4; ++c) acc[r][c] = f32x4{0.f, 0.f, 0.f, 0.f};
  const int ar = t >> 1, kh = t & 1;
  u16* sA0 = sA + ((ar >> 4) * 4 + kh * 2) * 128 + (ar & 15) * 8;
  for (int ks = 0; ks < 8; ++ks) {
    __syncthreads();
    const float* ap = A + (size_t)(r0 + ar) * CDIM + ks * 32 + kh * 16;
    const float4 f0 = *(const float4*)ap;
    const float4 f1 = *(const float4*)(ap + 4);
    const float4 f2 = *(const float4*)(ap + 8);
    const float4 f3 = *(const float4*)(ap + 12);
    uint4 p0, p1;
    p0.x = pack_bf16_rne(f0.x, f0.y);
    p0.y = pack_bf16_rne(f0.z, f0.w);
    p0.z = pack_bf16_rne(f1.x, f1.y);
    p0.w = pack_bf16_rne(f1.z, f1.w);
    p1.x = pack_bf16_rne(f2.x, f2.y);
    p1.y = pack_bf16_rne(f2.z, f2.w);
    p1.z = pack_bf16_rne(f3.x, f3.y);
    p1.w = pack_bf16_rne(f3.z, f3.w);
    *(uint4*)sA0 = p0;
    *(uint4*)(sA0 + 128) = p1;
    const u16* wsrc = Wf + ((size_t)ks * 96 + cb * 32) * 128 + t * 16;
    *(uint4*)(sB + t * 16) = *(const uint4*)wsrc;
    *(uint4*)(sB + t * 16 + 8) = *(const uint4*)(wsrc + 8);
    __syncthreads();
    bf16x8 af[4];
#pragma unroll
    for (int r = 0; r < 4; ++r)
      af[r] = *(const bf16x8*)(sA + ((wr * 4 + r) * 4 + fq) * 128 + fr * 8);
#pragma unroll
    for (int c = 0; c < 4; ++c) {
      const bf16x8 bf = *(const bf16x8*)(sB + ((wc * 4 + c) * 4 + fq) * 128 + fr * 8);
#pragma unroll
      for (int r = 0; r < 4; ++r)
        acc[r][c] = __builtin_amdgcn_mfma_f32_16x16x32_bf16(af[r], bf, acc[r][c], 0, 0, 0);
    }
  }
  const int rq = fq * 4;
#pragma unroll
  for (int c = 0; c < 4; ++c) {
    const int col = cb * 128 + wc * 64 + c * 16 + fr;
    const float bz = bias[col];
#pragma unroll
    for (int r = 0; r < 4; ++r) {
      const int row0 = r0 + wr * 64 + r * 16 + rq;
#pragma unroll
      for (int g = 0; g < 4; ++g) {
        const float v = acc[r][c][g] + bz;
        if (col < 256)
          outO[(size_t)(row0 + g) * 256 + col] = v;
        else
          outA[(size_t)(row0 + g) * 128 + (col - 256)] = v;
      }
    }
  }
}

// GEMM 3: out = samp(bf16) @ WfO + bo -> f32 out, N=256
__global__ __launch_bounds__(256) void gemm_out(
    const u16* __restrict__ A, const u16* __restrict__ Wf,
    const float* __restrict__ bias, float* __restrict__ out) {
  __shared__ u16 sA[128 * 32];
  __shared__ u16 sB[128 * 32];
  const int rb = blockIdx.x >> 1, cb = blockIdx.x & 1;
  const int r0 = rb * 128;
  const int t = threadIdx.x, l = t & 63, wv = t >> 6;
  const int wr = wv >> 1, wc = wv & 1;
  const int fq = l >> 4, fr = l & 15;
  f32x4 acc[4][4];
#pragma unroll
  for (int r = 0; r < 4; ++r)
#pragma unroll
    for (int c = 0; c < 4; ++c) acc[r][c] = f32x4{0.f, 0.f, 0.f, 0.f};
  const int ar = t >> 1, kh = t & 1;
  u16* sA0 = sA + ((ar >> 4) * 4 + kh * 2) * 128 + (ar & 15) * 8;
  for (int ks = 0; ks < 8; ++ks) {
    __syncthreads();
    const u16* ap = A + (size_t)(r0 + ar) * CDIM + ks * 32 + kh * 16;
    const uint4 p0 = *(const uint4*)ap;
    const uint4 p1 = *(const uint4*)(ap + 8);
    *(uint4*)sA0 = p0;
    *(uint4*)(sA0 + 128) = p1;
    const u16* wsrc = Wf + ((size_t)ks * 64 + cb * 32) * 128 + t * 16;
    *(uint4*)(sB + t * 16) = *(const uint4*)wsrc;
    *(uint4*)(sB + t * 16 + 8) = *(const uint4*)(wsrc + 8);
    __syncthreads();
    bf16x8 af[4];
#pragma unroll
    for (int r = 0; r < 4; ++r)
      af[r] = *(const bf16x8*)(sA + ((wr * 4 + r) * 4 + fq) * 128 + fr * 8);
#pragma unroll
    for (int c = 0; c < 4; ++c) {
      const bf16x8 bf = *(const bf16x8*)(sB + ((wc * 4 + c) * 4 + fq) * 128 + fr * 8);
#pragma unroll
      for (int r = 0; r < 4; ++r)
        acc[r][c] = __builtin_amdgcn_mfma_f32_16x16x32_bf16(af[r], bf, acc[r][c], 0, 0, 0);
    }
  }
  const int rq = fq * 4;
#pragma unroll
  for (int c = 0; c < 4; ++c) {
    const int col = cb * 128 + wc * 64 + c * 16 + fr;
    const float bz = bias[col];
#pragma unroll
    for (int r = 0; r < 4; ++r) {
      const int row0 = r0 + wr * 64 + r * 16 + rq;
#pragma unroll
      for (int g = 0; g < 4; ++g)
        out[(size_t)(row0 + g) * 256 + col] = acc[r][c][g] + bz;
    }
  }
}

// ---------- sampler: 8 queries per 256-thread block ----------
__global__ __launch_bounds__(256) void msda_sample3(
    const u16* __restrict__ value, const float* __restrict__ off,
    const float* __restrict__ attnl, const float* __restrict__ refp,
    u16* __restrict__ out) {
  __shared__ float s_aw[64 * 17];
  __shared__ uint4 s_idx[16 * 64];
  __shared__ float4 s_w[16 * 64];
  const int t = threadIdx.x;
  const int bq0 = blockIdx.x * 8;

  if (t < 64) {
    const float* lg = attnl + (size_t)(bq0 + (t >> 3)) * 128 + (t & 7) * 16;
    float e[16];
    float m = -1e30f;
#pragma unroll
    for (int i = 0; i < 16; ++i) {
      e[i] = lg[i];
      m = fmaxf(m, e[i]);
    }
    float s = 0.f;
#pragma unroll
    for (int i = 0; i < 16; ++i) {
      e[i] = __expf(e[i] - m);
      s += e[i];
    }
    const float inv = 1.f / s;
#pragma unroll
    for (int i = 0; i < 16; ++i) s_aw[t * 17 + i] = e[i] * inv;
  }
  __syncthreads();

#pragma unroll
  for (int rr = 0; rr < 4; ++rr) {
    const int id = t + rr * 256;
    const int qh = id & 63, lp = id >> 6;
    const int q = qh >> 3, h = qh & 7, lv = lp >> 2, p = lp & 3;
    const int bq = bq0 + q;
    const int Wl = 128 >> lv;
    const int st = (lv == 0) ? 0 : (lv == 1) ? 16384 : (lv == 2) ? 20480 : 21504;
    const float ox = off[(size_t)bq * 256 + ((h * 4 + lv) * 4 + p) * 2];
    const float oy = off[(size_t)bq * 256 + ((h * 4 + lv) * 4 + p) * 2 + 1];
    const float rx = refp[(size_t)bq * 8 + lv * 2];
    const float ry = refp[(size_t)bq * 8 + lv * 2 + 1];
    const float aw = s_aw[qh * 17 + lp];
    const float x = rx * (float)Wl + ox - 0.5f;
    const float y = ry * (float)Wl + oy - 0.5f;
    const float xf = floorf(x), yf = floorf(y);
    const int x0 = (int)xf, y0 = (int)yf;
    const float lw = x - xf, lh = y - yf;
    const float hw = 1.f - lw, hh = 1.f - lh;
    const int ixs[4] = {x0, x0 + 1, x0, x0 + 1};
    const int iys[4] = {y0, y0, y0 + 1, y0 + 1};
    const float wts[4] = {hw * hh, lw * hh, hw * lh, lw * lh};
    u32 rows[4];
    float ws4[4];
#pragma unroll
    for (int c = 0; c < 4; ++c) {
      const int ix = ixs[c], iy = iys[c];
      const bool valid = (ix >= 0) & (ix < Wl) & (iy >= 0) & (iy < Wl);
      int idx = iy * Wl + ix;
      idx = max(0, min(idx, Wl * Wl - 1));
      rows[c] = (u32)(st + idx);
      ws4[c] = valid ? (wts[c] * aw) : 0.f;
    }
    uint4 iv;
    iv.x = rows[0];
    iv.y = rows[1];
    iv.z = rows[2];
    iv.w = rows[3];
    s_idx[lp * 64 + qh] = iv;
    s_w[lp * 64 + qh] = make_float4(ws4[0], ws4[1], ws4[2], ws4[3]);
  }
  __syncthreads();

  const int q = t >> 5, h = (t >> 2) & 7, dg = t & 3;
  const int qh = q * 8 + h;
  const int bq = bq0 + q;
  const u16* vp = value + (size_t)((bq >= LQ_) ? LIN_ : 0) * CDIM + h * 32 + dg * 8;
  float a0 = 0.f, a1 = 0.f, a2 = 0.f, a3 = 0.f;
  float a4 = 0.f, a5 = 0.f, a6 = 0.f, a7 = 0.f;
#pragma unroll 4
  for (int lp = 0; lp < 16; ++lp) {
    const uint4 iv = s_idx[lp * 64 + qh];
    const float4 wv = s_w[lp * 64 + qh];
    const u32 rows[4] = {iv.x, iv.y, iv.z, iv.w};
    const float ww[4] = {wv.x, wv.y, wv.z, wv.w};
#pragma unroll
    for (int c = 0; c < 4; ++c) {
      const uint4 d = *(const uint4*)(vp + (size_t)rows[c] * CDIM);
      const float w = ww[c];
      a0 += w * bflo(d.x);
      a1 += w * bfhi(d.x);
      a2 += w * bflo(d.y);
      a3 += w * bfhi(d.y);
      a4 += w * bflo(d.z);
      a5 += w * bfhi(d.z);
      a6 += w * bflo(d.w);
      a7 += w * bfhi(d.w);
    }
  }
  uint4 o;
  o.x = pack_bf16_rne(a0, a1);
  o.y = pack_bf16_rne(a2, a3);
  o.z = pack_bf16_rne(a4, a5);
  o.w = pack_bf16_rne(a6, a7);
  *(uint4*)(out + (size_t)bq * CDIM + h * 32 + dg * 8) = o;
}

extern "C" void kernel_launch(void* const* d_in, const int* in_sizes, int n_in,
                              void* d_out, int out_size, void* d_ws, size_t ws_size,
                              hipStream_t stream) {
  const float* query = (const float*)d_in[0];
  const float* refp = (const float*)d_in[1];
  const float* inflat = (const float*)d_in[2];
  const float* Wv = (const float*)d_in[3];
  const float* bv = (const float*)d_in[4];
  const float* Wof = (const float*)d_in[5];
  const float* bof = (const float*)d_in[6];
  const float* Wa = (const float*)d_in[7];
  const float* ba = (const float*)d_in[8];
  const float* Wo = (const float*)d_in[9];
  const float* bo = (const float*)d_in[10];
  float* out = (float*)d_out;

  const int M = 2 * LQ_;  // 43520

  u16* ws_value = (u16*)d_ws;                           // M*256 bf16
  u16* ws_samp = ws_value + (size_t)M * 256;            // M*256 bf16
  float* ws_off = (float*)(ws_samp + (size_t)M * 256);  // M*256 f32
  float* ws_attn = ws_off + (size_t)M * 256;            // M*128 f32
  u16* WfV = (u16*)(ws_attn + (size_t)M * 128);         // 256*256 bf16
  u16* WfC = WfV + 256 * 256;                           // 256*384 bf16
  u16* WfO = WfC + 384 * 256;                           // 256*256 bf16
  float* bcat = (float*)(WfO + 256 * 256);              // 384 f32

  conv_all<<<dim3(114), dim3(256), 0, stream>>>(Wv, Wof, Wa, Wo, bof, ba, WfV, WfC, WfO,
                                                bcat);
  gemm_value<<<dim3(680), dim3(256), 0, stream>>>(inflat, WfV, bv, ws_value);
  gemm_qc<<<dim3(1020), dim3(256), 0, stream>>>(query, WfC, bcat, ws_off, ws_attn);
  msda_sample3<<<dim3(M / 8), dim3(256), 0, stream>>>(ws_value, ws_off, ws_attn, refp,
                                                      ws_samp);
  gemm_out<<<dim3(680), dim3(256), 0, stream>>>(ws_samp, WfO, bo, out);
}